// Round 6
// baseline (2750.289 us; speedup 1.0000x reference)
//
#include <hip/hip_runtime.h>
#include <hip/hip_bf16.h>
#include <math.h>

#define N_NODES 100000
#define N_EDGES 3200000
#define F0 489
#define KPAD 512
#define BSHIFT2 7                 // 128-node buckets
#define NBUCK2 782                // ceil(100000/128)
#define BW_CHUNK 16384
#define SRC_MASK 0x1FFFF          // 17 bits for src (< 131072)

typedef __attribute__((ext_vector_type(8))) short short8;
typedef __attribute__((ext_vector_type(4))) float f32x4;
typedef unsigned short ushort_t;
typedef unsigned int uint_t;

__device__ __forceinline__ short f2bf(float v) {
    return __builtin_bit_cast(short, __float2bfloat16(v));
}
__device__ __forceinline__ float bf2f(ushort_t u) {
    union { uint_t i; float f; } c;
    c.i = ((uint_t)u) << 16;
    return c.f;
}

// ---------------- zero int buffer ----------------
__global__ void k_zero(int* a, int n) {
    int i = blockIdx.x * blockDim.x + threadIdx.x;
    if (i < n) a[i] = 0;
}

// ---------------- integer degree histogram (dst) ----------------
__global__ void k_count(const int* __restrict__ dst, int* deg) {
    int e = blockIdx.x * blockDim.x + threadIdx.x;
    if (e < N_EDGES) atomicAdd(&deg[dst[e]], 1);
}

// ---------------- dinv = rsqrt(deg+1) ----------------
__global__ void k_dinv(const int* __restrict__ deg, float* dinv) {
    int i = blockIdx.x * blockDim.x + threadIdx.x;
    if (i < N_NODES) dinv[i] = rsqrtf((float)deg[i] + 1.0f);
}

// ---------------- per-bucket edge counts from deg (exclusive ownership) ----------------
// block covers 256 nodes = buckets 2b, 2b+1
__global__ __launch_bounds__(256) void k_bucketsum(const int* __restrict__ deg,
                                                   int* __restrict__ bcnt) {
    __shared__ int s[2];
    if (threadIdx.x < 2) s[threadIdx.x] = 0;
    __syncthreads();
    int i = blockIdx.x * 256 + threadIdx.x;
    int v = (i < N_NODES) ? deg[i] : 0;
    for (int off = 32; off; off >>= 1) v += __shfl_down(v, off, 64);
    int wave = threadIdx.x >> 6;
    if ((threadIdx.x & 63) == 0) atomicAdd(&s[wave >> 1], v);
    __syncthreads();
    if (threadIdx.x < 2) bcnt[blockIdx.x * 2 + threadIdx.x] = s[threadIdx.x];
}

// ---------------- 1024-wide scan of bucket counts -> bbase (exclusive) ----------------
__global__ __launch_bounds__(1024) void k_bscan(const int* __restrict__ bcnt,
                                                int* __restrict__ bbase) {
    __shared__ int tmp[1024];
    int i = threadIdx.x;
    int v = (i < NBUCK2) ? bcnt[i] : 0;
    tmp[i] = v;
    __syncthreads();
    for (int off = 1; off < 1024; off <<= 1) {
        int t = (i >= off) ? tmp[i - off] : 0;
        __syncthreads();
        tmp[i] += t;
        __syncthreads();
    }
    bbase[i] = tmp[i] - v;          // exclusive
    if (i == 1023) bbase[1024] = tmp[i];
}

// ---------------- bin edges into bucket-contiguous packed u32 stream ----------------
__global__ __launch_bounds__(256) void k_binwrite(const int* __restrict__ src,
                                                  const int* __restrict__ dst,
                                                  const int* __restrict__ bbase,
                                                  int* __restrict__ bcur,
                                                  uint_t* __restrict__ binned) {
    __shared__ int lcnt[NBUCK2];
    __shared__ int lpos[NBUCK2];
    for (int b = threadIdx.x; b < NBUCK2; b += 256) lcnt[b] = 0;
    __syncthreads();
    int e0 = blockIdx.x * BW_CHUNK;
    int e1 = e0 + BW_CHUNK; if (e1 > N_EDGES) e1 = N_EDGES;
    for (int e = e0 + threadIdx.x; e < e1; e += 256)
        atomicAdd(&lcnt[dst[e] >> BSHIFT2], 1);
    __syncthreads();
    for (int b = threadIdx.x; b < NBUCK2; b += 256) {
        int c = lcnt[b];
        lpos[b] = (c > 0) ? (bbase[b] + atomicAdd(&bcur[b], c)) : 0;
    }
    __syncthreads();
    for (int e = e0 + threadIdx.x; e < e1; e += 256) {
        int d = dst[e];
        int b = d >> BSHIFT2;
        int pos = atomicAdd(&lpos[b], 1);
        binned[pos] = (uint_t)src[e] | ((uint_t)(d & 127) << 17);
    }
}

// ---------------- W1 -> bf16, transposed+padded: Wt[n][k], n<64, k<512 ----------------
__global__ void k_cvtW(const float* __restrict__ W1, short* __restrict__ Wt) {
    int i = blockIdx.x * 256 + threadIdx.x;
    if (i < 64 * KPAD) {
        int n = i >> 9, k = i & (KPAD - 1);
        float v = (k < F0) ? W1[k * 64 + n] : 0.f;
        Wt[i] = f2bf(v);
    }
}

// ---------------- layer 1 MFMA GEMM: g1 = bf16( dinv .* (x @ W1) ) ----------------
__global__ __launch_bounds__(256) void k_gemm1_mfma(const float* __restrict__ x,
                                                    const short* __restrict__ Wt,
                                                    const float* __restrict__ dinv,
                                                    ushort_t* __restrict__ g1) {
    int wave = threadIdx.x >> 6;
    int lane = threadIdx.x & 63;
    int quad = lane >> 4;
    int m = lane & 15;
    int row0 = blockIdx.x * 64 + wave * 16;
    int row = row0 + m;
    int rowc = row < N_NODES ? row : N_NODES - 1;
    const float* xr = x + (size_t)rowc * F0;

    f32x4 acc0 = {0.f, 0.f, 0.f, 0.f};
    f32x4 acc1 = {0.f, 0.f, 0.f, 0.f};
    f32x4 acc2 = {0.f, 0.f, 0.f, 0.f};
    f32x4 acc3 = {0.f, 0.f, 0.f, 0.f};

    const short* wb = Wt + m * KPAD + quad * 8;

    for (int ks = 0; ks < 15; ks++) {
        int kb = ks * 32 + quad * 8;
        short8 af;
#pragma unroll
        for (int j = 0; j < 8; j++) af[j] = f2bf(xr[kb + j]);
        const short* wk = wb + ks * 32;
        short8 b0 = *(const short8*)(wk);
        short8 b1 = *(const short8*)(wk + 16 * KPAD);
        short8 b2 = *(const short8*)(wk + 32 * KPAD);
        short8 b3 = *(const short8*)(wk + 48 * KPAD);
        acc0 = __builtin_amdgcn_mfma_f32_16x16x32_bf16(af, b0, acc0, 0, 0, 0);
        acc1 = __builtin_amdgcn_mfma_f32_16x16x32_bf16(af, b1, acc1, 0, 0, 0);
        acc2 = __builtin_amdgcn_mfma_f32_16x16x32_bf16(af, b2, acc2, 0, 0, 0);
        acc3 = __builtin_amdgcn_mfma_f32_16x16x32_bf16(af, b3, acc3, 0, 0, 0);
    }
    {   // ks = 15 tail: guard per element
        int kb = 480 + quad * 8;
        short8 af;
#pragma unroll
        for (int j = 0; j < 8; j++) af[j] = (kb + j < F0) ? f2bf(xr[kb + j]) : (short)0;
        const short* wk = wb + 15 * 32;
        short8 b0 = *(const short8*)(wk);
        short8 b1 = *(const short8*)(wk + 16 * KPAD);
        short8 b2 = *(const short8*)(wk + 32 * KPAD);
        short8 b3 = *(const short8*)(wk + 48 * KPAD);
        acc0 = __builtin_amdgcn_mfma_f32_16x16x32_bf16(af, b0, acc0, 0, 0, 0);
        acc1 = __builtin_amdgcn_mfma_f32_16x16x32_bf16(af, b1, acc1, 0, 0, 0);
        acc2 = __builtin_amdgcn_mfma_f32_16x16x32_bf16(af, b2, acc2, 0, 0, 0);
        acc3 = __builtin_amdgcn_mfma_f32_16x16x32_bf16(af, b3, acc3, 0, 0, 0);
    }

#pragma unroll
    for (int r = 0; r < 4; r++) {
        int orow = row0 + quad * 4 + r;
        if (orow < N_NODES) {
            float s = dinv[orow];
            ushort_t* gr = g1 + (size_t)orow * 64 + m;
            gr[0]  = (ushort_t)f2bf(s * acc0[r]);
            gr[16] = (ushort_t)f2bf(s * acc1[r]);
            gr[32] = (ushort_t)f2bf(s * acc2[r]);
            gr[48] = (ushort_t)f2bf(s * acc3[r]);
        }
    }
}

// ---------------- agg64: one block per 128-node bucket, LDS accumulator ----------------
__global__ __launch_bounds__(256) void k_agg64(const int* __restrict__ bbase,
                                               const uint_t* __restrict__ binned,
                                               const ushort_t* __restrict__ g,
                                               float* __restrict__ agg) {
    __shared__ float acc[128 * 64];  // 32 KB
    int b = blockIdx.x;
    int node0 = b << BSHIFT2;
    // init with self-loop message
    for (int i = threadIdx.x; i < 128 * 64; i += 256) {
        int node = node0 + (i >> 6);
        acc[i] = (node < N_NODES) ? bf2f(g[(size_t)node * 64 + (i & 63)]) : 0.f;
    }
    __syncthreads();
    int lo = bbase[b], hi = bbase[b + 1];
    int wave = threadIdx.x >> 6;
    int lane = threadIdx.x & 63;
    for (int base = lo + wave * 64; base < hi; base += 256) {
        int n = hi - base; if (n > 64) n = 64;
        uint_t ev = binned[base + (lane < n ? lane : n - 1)];
        int i = 0;
        for (; i + 2 <= n; i += 2) {
            uint_t v0 = __shfl(ev, i, 64);
            uint_t v1 = __shfl(ev, i + 1, 64);
            float x0 = bf2f(g[(size_t)(v0 & SRC_MASK) * 64 + lane]);
            float x1 = bf2f(g[(size_t)(v1 & SRC_MASK) * 64 + lane]);
            unsafeAtomicAdd(&acc[(v0 >> 17) * 64 + lane], x0);
            unsafeAtomicAdd(&acc[(v1 >> 17) * 64 + lane], x1);
        }
        if (i < n) {
            uint_t v0 = __shfl(ev, i, 64);
            float x0 = bf2f(g[(size_t)(v0 & SRC_MASK) * 64 + lane]);
            unsafeAtomicAdd(&acc[(v0 >> 17) * 64 + lane], x0);
        }
    }
    __syncthreads();
    for (int i = threadIdx.x; i < 128 * 64; i += 256) {
        int node = node0 + (i >> 6);
        if (node < N_NODES) agg[(size_t)node * 64 + (i & 63)] = acc[i];
    }
}

// ---------------- agg32: half-wave per edge ----------------
__global__ __launch_bounds__(256) void k_agg32(const int* __restrict__ bbase,
                                               const uint_t* __restrict__ binned,
                                               const ushort_t* __restrict__ g,
                                               float* __restrict__ agg) {
    __shared__ float acc[128 * 32];  // 16 KB
    int b = blockIdx.x;
    int node0 = b << BSHIFT2;
    for (int i = threadIdx.x; i < 128 * 32; i += 256) {
        int node = node0 + (i >> 5);
        acc[i] = (node < N_NODES) ? bf2f(g[(size_t)node * 32 + (i & 31)]) : 0.f;
    }
    __syncthreads();
    int lo = bbase[b], hi = bbase[b + 1];
    int wave = threadIdx.x >> 6;
    int lane = threadIdx.x & 63;
    int half = lane >> 5;
    int f = lane & 31;
    for (int base = lo + wave * 64; base < hi; base += 256) {
        int n = hi - base; if (n > 64) n = 64;
        uint_t ev = binned[base + (lane < n ? lane : n - 1)];
        int i = 0;
        for (; i + 2 <= n; i += 2) {
            uint_t v = __shfl(ev, i + half, 64);
            float xv = bf2f(g[(size_t)(v & SRC_MASK) * 32 + f]);
            unsafeAtomicAdd(&acc[(v >> 17) * 32 + f], xv);
        }
        if (i < n && half == 0) {
            uint_t v = __shfl(ev, i, 64);
            float xv = bf2f(g[(size_t)(v & SRC_MASK) * 32 + f]);
            unsafeAtomicAdd(&acc[(v >> 17) * 32 + f], xv);
        }
    }
    __syncthreads();
    for (int i = threadIdx.x; i < 128 * 32; i += 256) {
        int node = node0 + (i >> 5);
        if (node < N_NODES) agg[(size_t)node * 32 + (i & 31)] = acc[i];
    }
}

// ---------------- agg2: thread per edge ----------------
__global__ __launch_bounds__(256) void k_agg2(const int* __restrict__ bbase,
                                              const uint_t* __restrict__ binned,
                                              const float* __restrict__ g,
                                              float* __restrict__ agg) {
    __shared__ float acc[128 * 2];
    int b = blockIdx.x;
    int node0 = b << BSHIFT2;
    for (int i = threadIdx.x; i < 256; i += 256) {
        int node = node0 + (i >> 1);
        acc[i] = (node < N_NODES) ? g[(size_t)node * 2 + (i & 1)] : 0.f;
    }
    __syncthreads();
    int lo = bbase[b], hi = bbase[b + 1];
    for (int j = lo + threadIdx.x; j < hi; j += 256) {
        uint_t v = binned[j];
        int s = v & SRC_MASK;
        int dl = v >> 17;
        unsafeAtomicAdd(&acc[dl * 2 + 0], g[(size_t)s * 2 + 0]);
        unsafeAtomicAdd(&acc[dl * 2 + 1], g[(size_t)s * 2 + 1]);
    }
    __syncthreads();
    for (int i = threadIdx.x; i < 256; i += 256) {
        int node = node0 + (i >> 1);
        if (node < N_NODES) agg[(size_t)node * 2 + (i & 1)] = acc[i];
    }
}

// ---------------- layer 2: g2 = bf16( dinv .* (relu(dinv*agg1+b1) @ W2) ) ----------------
__global__ __launch_bounds__(256) void k_layer2(const float* __restrict__ agg1,
                                                const float* __restrict__ dinv,
                                                const float* __restrict__ b1,
                                                const float* __restrict__ W2,
                                                ushort_t* __restrict__ g2) {
    __shared__ float hs[32][65];
    __shared__ float Ws[64 * 32];
    for (int i = threadIdx.x; i < 64 * 32; i += 256) Ws[i] = W2[i];
    int row0 = blockIdx.x * 32;
    for (int i = threadIdx.x; i < 32 * 64; i += 256) {
        int r = i >> 6, f = i & 63;
        int row = row0 + r;
        float v = dinv[row] * agg1[(size_t)row * 64 + f] + b1[f];
        hs[r][f] = fmaxf(v, 0.f);
    }
    __syncthreads();
    int r = threadIdx.x >> 3;
    int j0 = (threadIdx.x & 7) * 4;
    int row = row0 + r;
    float a0 = 0.f, a1 = 0.f, a2 = 0.f, a3 = 0.f;
#pragma unroll 8
    for (int f = 0; f < 64; f++) {
        float h = hs[r][f];
        a0 += h * Ws[f * 32 + j0 + 0];
        a1 += h * Ws[f * 32 + j0 + 1];
        a2 += h * Ws[f * 32 + j0 + 2];
        a3 += h * Ws[f * 32 + j0 + 3];
    }
    float s = dinv[row];
    ushort_t* gr = g2 + (size_t)row * 32 + j0;
    gr[0] = (ushort_t)f2bf(s * a0);
    gr[1] = (ushort_t)f2bf(s * a1);
    gr[2] = (ushort_t)f2bf(s * a2);
    gr[3] = (ushort_t)f2bf(s * a3);
}

// ---------------- layer 3 ----------------
__global__ __launch_bounds__(256) void k_layer3(const float* __restrict__ agg2,
                                                const float* __restrict__ dinv,
                                                const float* __restrict__ b2,
                                                const float* __restrict__ W3,
                                                float* __restrict__ g3) {
    int row = blockIdx.x * blockDim.x + threadIdx.x;
    if (row >= N_NODES) return;
    float s = dinv[row];
    float t0 = 0.f, t1 = 0.f;
    const float4* ar = reinterpret_cast<const float4*>(agg2 + (size_t)row * 32);
#pragma unroll
    for (int q = 0; q < 8; q++) {
        float4 v = ar[q];
        float h;
        int f = q * 4;
        h = fmaxf(s * v.x + b2[f + 0], 0.f); t0 += h * W3[(f + 0) * 2]; t1 += h * W3[(f + 0) * 2 + 1];
        h = fmaxf(s * v.y + b2[f + 1], 0.f); t0 += h * W3[(f + 1) * 2]; t1 += h * W3[(f + 1) * 2 + 1];
        h = fmaxf(s * v.z + b2[f + 2], 0.f); t0 += h * W3[(f + 2) * 2]; t1 += h * W3[(f + 2) * 2 + 1];
        h = fmaxf(s * v.w + b2[f + 3], 0.f); t0 += h * W3[(f + 3) * 2]; t1 += h * W3[(f + 3) * 2 + 1];
    }
    g3[(size_t)row * 2 + 0] = s * t0;
    g3[(size_t)row * 2 + 1] = s * t1;
}

// ---------------- final log_softmax ----------------
__global__ void k_final(const float* __restrict__ agg3,
                        const float* __restrict__ dinv,
                        const float* __restrict__ b3,
                        float* __restrict__ out) {
    int row = blockIdx.x * blockDim.x + threadIdx.x;
    if (row >= N_NODES) return;
    float s = dinv[row];
    float z0 = s * agg3[(size_t)row * 2 + 0] + b3[0];
    float z1 = s * agg3[(size_t)row * 2 + 1] + b3[1];
    float m = fmaxf(z0, z1);
    float lse = m + logf(expf(z0 - m) + expf(z1 - m));
    out[(size_t)row * 2 + 0] = z0 - lse;
    out[(size_t)row * 2 + 1] = z1 - lse;
}

extern "C" void kernel_launch(void* const* d_in, const int* in_sizes, int n_in,
                              void* d_out, int out_size, void* d_ws, size_t ws_size,
                              hipStream_t stream) {
    const float* x  = (const float*)d_in[0];
    const int*   ei = (const int*)d_in[1];
    const float* W1 = (const float*)d_in[2];
    const float* b1 = (const float*)d_in[3];
    const float* W2 = (const float*)d_in[4];
    const float* b2 = (const float*)d_in[5];
    const float* W3 = (const float*)d_in[6];
    const float* b3 = (const float*)d_in[7];
    float* out = (float*)d_out;

    const int* src = ei;
    const int* dst = ei + N_EDGES;

    // ---- workspace layout (int elements) ----
    int* deg_i  = (int*)d_ws;                    // 100096
    int* bcnt   = deg_i + 100096;                // 1024
    int* bcur   = bcnt + 1024;                   // 1024   (zero deg..bcur = 102144)
    int* bbase  = bcur + 1024;                   // 1025 -> pad 1028
    float* dinv = (float*)(bbase + 1028);        // 100000
    short* Wt   = (short*)(dinv + 100000);       // 32768 shorts = 16384 ints
    uint_t* binned = (uint_t*)((int*)Wt + 16384);         // 3.2M u32 = 12.8 MB
    ushort_t* gbuf = (ushort_t*)(binned + N_EDGES);       // N*64 ushort = 12.8 MB
    float* aggF = (float*)(gbuf + (size_t)N_NODES * 64);  // N*64 fp32 = 25.6 MB

    ushort_t* gb1 = gbuf;
    ushort_t* gb2 = gbuf;
    float* g3     = (float*)gbuf;   // gb2 dead after agg32
    float* agg1 = aggF;
    float* agg2 = aggF;
    float* agg3 = aggF;

    const int TB = 256;
    int nb_nodes = (N_NODES + TB - 1) / TB;      // 391
    int nb_edges = (N_EDGES + TB - 1) / TB;      // 12500
    int nb_bw    = (N_EDGES + BW_CHUNK - 1) / BW_CHUNK;  // 196

    k_zero<<<(102144 + TB - 1) / TB, TB, 0, stream>>>(deg_i, 102144);
    k_count<<<nb_edges, TB, 0, stream>>>(dst, deg_i);
    k_dinv<<<nb_nodes, TB, 0, stream>>>(deg_i, dinv);
    k_bucketsum<<<nb_nodes, TB, 0, stream>>>(deg_i, bcnt);
    k_bscan<<<1, 1024, 0, stream>>>(bcnt, bbase);
    k_binwrite<<<nb_bw, TB, 0, stream>>>(src, dst, bbase, bcur, binned);
    k_cvtW<<<(64 * KPAD + 255) / 256, 256, 0, stream>>>(W1, Wt);

    k_gemm1_mfma<<<(N_NODES + 63) / 64, TB, 0, stream>>>(x, Wt, dinv, gb1);
    k_agg64<<<NBUCK2, TB, 0, stream>>>(bbase, binned, gb1, agg1);

    k_layer2<<<N_NODES / 32, TB, 0, stream>>>(agg1, dinv, b1, W2, gb2);
    k_agg32<<<NBUCK2, TB, 0, stream>>>(bbase, binned, gb2, agg2);

    k_layer3<<<nb_nodes, TB, 0, stream>>>(agg2, dinv, b2, W3, g3);
    k_agg2<<<NBUCK2, TB, 0, stream>>>(bbase, binned, g3, agg3);

    k_final<<<nb_nodes, TB, 0, stream>>>(agg3, dinv, b3, out);
}

// Round 7
// 739.939 us; speedup vs baseline: 3.7169x; 3.7169x over previous
//
#include <hip/hip_runtime.h>
#include <hip/hip_bf16.h>
#include <math.h>

#define N_NODES 100000
#define N_EDGES 3200000
#define F0 489
#define KPAD 512
#define BSHIFT2 7                 // 128-node buckets
#define NBUCK2 782                // ceil(100000/128)
#define BW_CHUNK 16384
#define SRC_MASK 0x1FFFF          // 17 bits for src (< 131072)

typedef __attribute__((ext_vector_type(8))) short short8;
typedef __attribute__((ext_vector_type(4))) float f32x4;
typedef unsigned short ushort_t;
typedef unsigned int uint_t;

__device__ __forceinline__ short f2bf(float v) {
    return __builtin_bit_cast(short, __float2bfloat16(v));
}
__device__ __forceinline__ float bf2f(ushort_t u) {
    union { uint_t i; float f; } c;
    c.i = ((uint_t)u) << 16;
    return c.f;
}

// ---------------- zero int buffer ----------------
__global__ void k_zero(int* a, int n) {
    int i = blockIdx.x * blockDim.x + threadIdx.x;
    if (i < n) a[i] = 0;
}

// ---------------- bucket histogram (LDS-aggregated) ----------------
__global__ __launch_bounds__(256) void k_bcount(const int* __restrict__ dst,
                                                int* __restrict__ bcnt) {
    __shared__ int lc[NBUCK2];
    for (int b = threadIdx.x; b < NBUCK2; b += 256) lc[b] = 0;
    __syncthreads();
    for (int e = blockIdx.x * 256 + threadIdx.x; e < N_EDGES; e += gridDim.x * 256)
        atomicAdd(&lc[dst[e] >> BSHIFT2], 1);
    __syncthreads();
    for (int b = threadIdx.x; b < NBUCK2; b += 256)
        if (lc[b] > 0) atomicAdd(&bcnt[b], lc[b]);
}

// ---------------- 1024-wide scan of bucket counts -> bbase (exclusive) ----------------
__global__ __launch_bounds__(1024) void k_bscan(const int* __restrict__ bcnt,
                                                int* __restrict__ bbase) {
    __shared__ int tmp[1024];
    int i = threadIdx.x;
    int v = (i < NBUCK2) ? bcnt[i] : 0;
    tmp[i] = v;
    __syncthreads();
    for (int off = 1; off < 1024; off <<= 1) {
        int t = (i >= off) ? tmp[i - off] : 0;
        __syncthreads();
        tmp[i] += t;
        __syncthreads();
    }
    bbase[i] = tmp[i] - v;          // exclusive
    if (i == 1023) bbase[1024] = tmp[i];
}

// ---------------- bin edges into bucket-contiguous packed u32 stream ----------------
__global__ __launch_bounds__(256) void k_binwrite(const int* __restrict__ src,
                                                  const int* __restrict__ dst,
                                                  const int* __restrict__ bbase,
                                                  int* __restrict__ bcur,
                                                  uint_t* __restrict__ binned) {
    __shared__ int lcnt[NBUCK2];
    __shared__ int lpos[NBUCK2];
    for (int b = threadIdx.x; b < NBUCK2; b += 256) lcnt[b] = 0;
    __syncthreads();
    int e0 = blockIdx.x * BW_CHUNK;
    int e1 = e0 + BW_CHUNK; if (e1 > N_EDGES) e1 = N_EDGES;
    for (int e = e0 + threadIdx.x; e < e1; e += 256)
        atomicAdd(&lcnt[dst[e] >> BSHIFT2], 1);
    __syncthreads();
    for (int b = threadIdx.x; b < NBUCK2; b += 256) {
        int c = lcnt[b];
        lpos[b] = (c > 0) ? (bbase[b] + atomicAdd(&bcur[b], c)) : 0;
    }
    __syncthreads();
    for (int e = e0 + threadIdx.x; e < e1; e += 256) {
        int d = dst[e];
        int b = d >> BSHIFT2;
        int pos = atomicAdd(&lpos[b], 1);
        binned[pos] = (uint_t)src[e] | ((uint_t)(d & 127) << 17);
    }
}

// ---------------- per-bucket CSR build: histogram + scan + scatter in one L2 window ----
// Also emits rowptr, dinv. One block per 128-node bucket.
__global__ __launch_bounds__(256) void k_fill3(const int* __restrict__ bbase,
                                               const uint_t* __restrict__ binned,
                                               int* __restrict__ rowptr,
                                               float* __restrict__ dinv,
                                               int* __restrict__ csr) {
    __shared__ int cnt[128];
    __shared__ int tmp[128];
    __shared__ int pos[128];
    int b = blockIdx.x;
    int node0 = b << BSHIFT2;
    int lo = bbase[b], hi = bbase[b + 1];
    int t = threadIdx.x;
    if (t < 128) cnt[t] = 0;
    __syncthreads();
    for (int i = lo + t; i < hi; i += 256)
        atomicAdd(&cnt[binned[i] >> 17], 1);
    __syncthreads();
    if (t < 128) tmp[t] = cnt[t];
    __syncthreads();
    for (int o = 1; o < 128; o <<= 1) {
        int v = 0;
        if (t < 128 && t >= o) v = tmp[t - o];
        __syncthreads();
        if (t < 128) tmp[t] += v;
        __syncthreads();
    }
    if (t < 128) {
        int excl = tmp[t] - cnt[t];
        pos[t] = excl;
        int node = node0 + t;
        if (node < N_NODES) {
            rowptr[node] = lo + excl;
            dinv[node] = rsqrtf((float)cnt[t] + 1.0f);
        } else if (node == N_NODES) {
            rowptr[node] = lo + excl;   // == N_EDGES (trailing counts are 0)
        }
    }
    __syncthreads();
    for (int i = lo + t; i < hi; i += 256) {
        uint_t v = binned[i];
        int dloc = v >> 17;
        int p = atomicAdd(&pos[dloc], 1);
        csr[lo + p] = (int)(v & SRC_MASK);
    }
}

// ---------------- W1 -> bf16, transposed+padded: Wt[n][k], n<64, k<512 ----------------
__global__ void k_cvtW(const float* __restrict__ W1, short* __restrict__ Wt) {
    int i = blockIdx.x * 256 + threadIdx.x;
    if (i < 64 * KPAD) {
        int n = i >> 9, k = i & (KPAD - 1);
        float v = (k < F0) ? W1[k * 64 + n] : 0.f;
        Wt[i] = f2bf(v);
    }
}

// ---------------- layer 1 MFMA GEMM: g1 = bf16( dinv .* (x @ W1) ) ----------------
__global__ __launch_bounds__(256) void k_gemm1_mfma(const float* __restrict__ x,
                                                    const short* __restrict__ Wt,
                                                    const float* __restrict__ dinv,
                                                    ushort_t* __restrict__ g1) {
    int wave = threadIdx.x >> 6;
    int lane = threadIdx.x & 63;
    int quad = lane >> 4;
    int m = lane & 15;
    int row0 = blockIdx.x * 64 + wave * 16;
    int row = row0 + m;
    int rowc = row < N_NODES ? row : N_NODES - 1;
    const float* xr = x + (size_t)rowc * F0;

    f32x4 acc0 = {0.f, 0.f, 0.f, 0.f};
    f32x4 acc1 = {0.f, 0.f, 0.f, 0.f};
    f32x4 acc2 = {0.f, 0.f, 0.f, 0.f};
    f32x4 acc3 = {0.f, 0.f, 0.f, 0.f};

    const short* wb = Wt + m * KPAD + quad * 8;

    for (int ks = 0; ks < 15; ks++) {
        int kb = ks * 32 + quad * 8;
        short8 af;
#pragma unroll
        for (int j = 0; j < 8; j++) af[j] = f2bf(xr[kb + j]);
        const short* wk = wb + ks * 32;
        short8 b0 = *(const short8*)(wk);
        short8 b1 = *(const short8*)(wk + 16 * KPAD);
        short8 b2 = *(const short8*)(wk + 32 * KPAD);
        short8 b3 = *(const short8*)(wk + 48 * KPAD);
        acc0 = __builtin_amdgcn_mfma_f32_16x16x32_bf16(af, b0, acc0, 0, 0, 0);
        acc1 = __builtin_amdgcn_mfma_f32_16x16x32_bf16(af, b1, acc1, 0, 0, 0);
        acc2 = __builtin_amdgcn_mfma_f32_16x16x32_bf16(af, b2, acc2, 0, 0, 0);
        acc3 = __builtin_amdgcn_mfma_f32_16x16x32_bf16(af, b3, acc3, 0, 0, 0);
    }
    {   // ks = 15 tail: guard per element
        int kb = 480 + quad * 8;
        short8 af;
#pragma unroll
        for (int j = 0; j < 8; j++) af[j] = (kb + j < F0) ? f2bf(xr[kb + j]) : (short)0;
        const short* wk = wb + 15 * 32;
        short8 b0 = *(const short8*)(wk);
        short8 b1 = *(const short8*)(wk + 16 * KPAD);
        short8 b2 = *(const short8*)(wk + 32 * KPAD);
        short8 b3 = *(const short8*)(wk + 48 * KPAD);
        acc0 = __builtin_amdgcn_mfma_f32_16x16x32_bf16(af, b0, acc0, 0, 0, 0);
        acc1 = __builtin_amdgcn_mfma_f32_16x16x32_bf16(af, b1, acc1, 0, 0, 0);
        acc2 = __builtin_amdgcn_mfma_f32_16x16x32_bf16(af, b2, acc2, 0, 0, 0);
        acc3 = __builtin_amdgcn_mfma_f32_16x16x32_bf16(af, b3, acc3, 0, 0, 0);
    }

#pragma unroll
    for (int r = 0; r < 4; r++) {
        int orow = row0 + quad * 4 + r;
        if (orow < N_NODES) {
            float s = dinv[orow];
            ushort_t* gr = g1 + (size_t)orow * 64 + m;
            gr[0]  = (ushort_t)f2bf(s * acc0[r]);
            gr[16] = (ushort_t)f2bf(s * acc1[r]);
            gr[32] = (ushort_t)f2bf(s * acc2[r]);
            gr[48] = (ushort_t)f2bf(s * acc3[r]);
        }
    }
}

// ---------------- gather, 64 bf16 features -> fp32 agg ----------------
__global__ __launch_bounds__(256) void k_gather64(const int* __restrict__ rowptr,
                                                  const int* __restrict__ csr,
                                                  const ushort_t* __restrict__ g,
                                                  float* __restrict__ agg) {
    int node = blockIdx.x * 4 + (threadIdx.x >> 6);
    int f = threadIdx.x & 63;
    int beg = rowptr[node], end = rowptr[node + 1];
    float acc = bf2f(g[(size_t)node * 64 + f]);  // self loop
    for (int j0 = beg; j0 < end; j0 += 64) {
        int n = end - j0;
        if (n > 64) n = 64;
        int e = csr[j0 + (f < n ? f : 0)];
        float a0 = 0.f, a1 = 0.f;
        int i = 0;
        for (; i + 2 <= n; i += 2) {
            int s0 = __shfl(e, i, 64);
            int s1 = __shfl(e, i + 1, 64);
            a0 += bf2f(g[(size_t)s0 * 64 + f]);
            a1 += bf2f(g[(size_t)s1 * 64 + f]);
        }
        if (i < n) {
            int s0 = __shfl(e, i, 64);
            a0 += bf2f(g[(size_t)s0 * 64 + f]);
        }
        acc += a0 + a1;
    }
    agg[(size_t)node * 64 + f] = acc;
}

// ---------------- gather, 32 bf16 features -> fp32 agg ----------------
__global__ __launch_bounds__(256) void k_gather32(const int* __restrict__ rowptr,
                                                  const int* __restrict__ csr,
                                                  const ushort_t* __restrict__ g,
                                                  float* __restrict__ agg) {
    int t = blockIdx.x * 256 + threadIdx.x;
    int node = t >> 5;
    int f = t & 31;
    int beg = rowptr[node], end = rowptr[node + 1];
    float acc = bf2f(g[(size_t)node * 32 + f]);
    for (int j0 = beg; j0 < end; j0 += 32) {
        int n = end - j0;
        if (n > 32) n = 32;
        int e = csr[j0 + (f < n ? f : 0)];
        float a0 = 0.f, a1 = 0.f;
        int i = 0;
        for (; i + 2 <= n; i += 2) {
            int s0 = __shfl(e, i, 32);
            int s1 = __shfl(e, i + 1, 32);
            a0 += bf2f(g[(size_t)s0 * 32 + f]);
            a1 += bf2f(g[(size_t)s1 * 32 + f]);
        }
        if (i < n) {
            int s0 = __shfl(e, i, 32);
            a0 += bf2f(g[(size_t)s0 * 32 + f]);
        }
        acc += a0 + a1;
    }
    agg[(size_t)node * 32 + f] = acc;
}

// ---------------- gather, 2 fp32 features ----------------
__global__ __launch_bounds__(256) void k_gather2(const int* __restrict__ rowptr,
                                                 const int* __restrict__ csr,
                                                 const float* __restrict__ g,
                                                 float* __restrict__ agg) {
    int t = blockIdx.x * 256 + threadIdx.x;
    if (t >= N_NODES * 2) return;
    int node = t >> 1;
    int f = t & 1;
    int beg = rowptr[node], end = rowptr[node + 1];
    float acc = g[(size_t)node * 2 + f];
    for (int j = beg; j < end; j++) {
        int s = csr[j];
        acc += g[(size_t)s * 2 + f];
    }
    agg[(size_t)node * 2 + f] = acc;
}

// ---------------- layer 2: g2 = bf16( dinv .* (relu(dinv*agg1+b1) @ W2) ) ----------------
__global__ __launch_bounds__(256) void k_layer2(const float* __restrict__ agg1,
                                                const float* __restrict__ dinv,
                                                const float* __restrict__ b1,
                                                const float* __restrict__ W2,
                                                ushort_t* __restrict__ g2) {
    __shared__ float hs[32][65];
    __shared__ float Ws[64 * 32];
    for (int i = threadIdx.x; i < 64 * 32; i += 256) Ws[i] = W2[i];
    int row0 = blockIdx.x * 32;
    for (int i = threadIdx.x; i < 32 * 64; i += 256) {
        int r = i >> 6, f = i & 63;
        int row = row0 + r;
        float v = dinv[row] * agg1[(size_t)row * 64 + f] + b1[f];
        hs[r][f] = fmaxf(v, 0.f);
    }
    __syncthreads();
    int r = threadIdx.x >> 3;
    int j0 = (threadIdx.x & 7) * 4;
    int row = row0 + r;
    float a0 = 0.f, a1 = 0.f, a2 = 0.f, a3 = 0.f;
#pragma unroll 8
    for (int f = 0; f < 64; f++) {
        float h = hs[r][f];
        a0 += h * Ws[f * 32 + j0 + 0];
        a1 += h * Ws[f * 32 + j0 + 1];
        a2 += h * Ws[f * 32 + j0 + 2];
        a3 += h * Ws[f * 32 + j0 + 3];
    }
    float s = dinv[row];
    ushort_t* gr = g2 + (size_t)row * 32 + j0;
    gr[0] = (ushort_t)f2bf(s * a0);
    gr[1] = (ushort_t)f2bf(s * a1);
    gr[2] = (ushort_t)f2bf(s * a2);
    gr[3] = (ushort_t)f2bf(s * a3);
}

// ---------------- layer 3 ----------------
__global__ __launch_bounds__(256) void k_layer3(const float* __restrict__ agg2,
                                                const float* __restrict__ dinv,
                                                const float* __restrict__ b2,
                                                const float* __restrict__ W3,
                                                float* __restrict__ g3) {
    int row = blockIdx.x * blockDim.x + threadIdx.x;
    if (row >= N_NODES) return;
    float s = dinv[row];
    float t0 = 0.f, t1 = 0.f;
    const float4* ar = reinterpret_cast<const float4*>(agg2 + (size_t)row * 32);
#pragma unroll
    for (int q = 0; q < 8; q++) {
        float4 v = ar[q];
        float h;
        int f = q * 4;
        h = fmaxf(s * v.x + b2[f + 0], 0.f); t0 += h * W3[(f + 0) * 2]; t1 += h * W3[(f + 0) * 2 + 1];
        h = fmaxf(s * v.y + b2[f + 1], 0.f); t0 += h * W3[(f + 1) * 2]; t1 += h * W3[(f + 1) * 2 + 1];
        h = fmaxf(s * v.z + b2[f + 2], 0.f); t0 += h * W3[(f + 2) * 2]; t1 += h * W3[(f + 2) * 2 + 1];
        h = fmaxf(s * v.w + b2[f + 3], 0.f); t0 += h * W3[(f + 3) * 2]; t1 += h * W3[(f + 3) * 2 + 1];
    }
    g3[(size_t)row * 2 + 0] = s * t0;
    g3[(size_t)row * 2 + 1] = s * t1;
}

// ---------------- final log_softmax ----------------
__global__ void k_final(const float* __restrict__ agg3,
                        const float* __restrict__ dinv,
                        const float* __restrict__ b3,
                        float* __restrict__ out) {
    int row = blockIdx.x * blockDim.x + threadIdx.x;
    if (row >= N_NODES) return;
    float s = dinv[row];
    float z0 = s * agg3[(size_t)row * 2 + 0] + b3[0];
    float z1 = s * agg3[(size_t)row * 2 + 1] + b3[1];
    float m = fmaxf(z0, z1);
    float lse = m + logf(expf(z0 - m) + expf(z1 - m));
    out[(size_t)row * 2 + 0] = z0 - lse;
    out[(size_t)row * 2 + 1] = z1 - lse;
}

extern "C" void kernel_launch(void* const* d_in, const int* in_sizes, int n_in,
                              void* d_out, int out_size, void* d_ws, size_t ws_size,
                              hipStream_t stream) {
    const float* x  = (const float*)d_in[0];
    const int*   ei = (const int*)d_in[1];
    const float* W1 = (const float*)d_in[2];
    const float* b1 = (const float*)d_in[3];
    const float* W2 = (const float*)d_in[4];
    const float* b2 = (const float*)d_in[5];
    const float* W3 = (const float*)d_in[6];
    const float* b3 = (const float*)d_in[7];
    float* out = (float*)d_out;

    const int* src = ei;
    const int* dst = ei + N_EDGES;

    // ---- workspace layout (int elements) ----
    int* bcnt   = (int*)d_ws;                    // 1024
    int* bcur   = bcnt + 1024;                   // 1024  (zero bcnt+bcur = 2048)
    int* bbase  = bcur + 1024;                   // 1028
    int* rowptr = bbase + 1028;                  // 100004
    int* csr    = rowptr + 100004;               // 3200000
    float* dinv = (float*)(csr + 3200000);       // 100000
    short* Wt   = (short*)(dinv + 100000);       // 32768 shorts = 16384 ints
    uint_t* binned = (uint_t*)((int*)Wt + 16384);         // 3.2M u32 = 12.8 MB
    ushort_t* gbuf = (ushort_t*)(binned + N_EDGES);       // N*64 ushort = 12.8 MB
    float* aggF = (float*)(gbuf + (size_t)N_NODES * 64);  // N*64 fp32 = 25.6 MB

    ushort_t* gb1 = gbuf;
    ushort_t* gb2 = gbuf;
    float* g3     = (float*)gbuf;   // gb2 dead after gather32
    float* agg1 = aggF;
    float* agg2 = aggF;
    float* agg3 = aggF;

    const int TB = 256;
    int nb_nodes = (N_NODES + TB - 1) / TB;      // 391
    int nb_bw    = (N_EDGES + BW_CHUNK - 1) / BW_CHUNK;  // 196

    k_zero<<<8, TB, 0, stream>>>(bcnt, 2048);
    k_bcount<<<2048, TB, 0, stream>>>(dst, bcnt);
    k_bscan<<<1, 1024, 0, stream>>>(bcnt, bbase);
    k_binwrite<<<nb_bw, TB, 0, stream>>>(src, dst, bbase, bcur, binned);
    k_fill3<<<NBUCK2, TB, 0, stream>>>(bbase, binned, rowptr, dinv, csr);
    k_cvtW<<<(64 * KPAD + 255) / 256, 256, 0, stream>>>(W1, Wt);

    k_gemm1_mfma<<<(N_NODES + 63) / 64, TB, 0, stream>>>(x, Wt, dinv, gb1);
    k_gather64<<<N_NODES / 4, TB, 0, stream>>>(rowptr, csr, gb1, agg1);

    k_layer2<<<N_NODES / 32, TB, 0, stream>>>(agg1, dinv, b1, W2, gb2);
    k_gather32<<<N_NODES / 8, TB, 0, stream>>>(rowptr, csr, gb2, agg2);

    k_layer3<<<nb_nodes, TB, 0, stream>>>(agg2, dinv, b2, W3, g3);
    k_gather2<<<(2 * N_NODES + TB - 1) / TB, TB, 0, stream>>>(rowptr, csr, g3, agg3);

    k_final<<<nb_nodes, TB, 0, stream>>>(agg3, dinv, b3, out);
}

// Round 8
// 710.250 us; speedup vs baseline: 3.8723x; 1.0418x over previous
//
#include <hip/hip_runtime.h>
#include <hip/hip_bf16.h>
#include <math.h>

#define N_NODES 100000
#define N_EDGES 3200000
#define F0 489
#define KPAD 512
#define BSHIFT2 7                 // 128-node buckets
#define NBUCK2 782                // ceil(100000/128)
#define BW_CHUNK 16384
#define SRC_MASK 0x1FFFF          // 17 bits for src (< 131072)

typedef __attribute__((ext_vector_type(8))) short short8;
typedef __attribute__((ext_vector_type(4))) float f32x4;
typedef unsigned short ushort_t;
typedef unsigned int uint_t;

__device__ __forceinline__ short f2bf(float v) {
    return __builtin_bit_cast(short, __float2bfloat16(v));
}
__device__ __forceinline__ float bf2f(ushort_t u) {
    union { uint_t i; float f; } c;
    c.i = ((uint_t)u) << 16;
    return c.f;
}
// bf16 pair in a dword -> two floats
__device__ __forceinline__ float pair_lo(uint_t v) {
    union { uint_t i; float f; } c; c.i = v << 16; return c.f;
}
__device__ __forceinline__ float pair_hi(uint_t v) {
    union { uint_t i; float f; } c; c.i = v & 0xffff0000u; return c.f;
}

// ---------------- zero int buffer ----------------
__global__ void k_zero(int* a, int n) {
    int i = blockIdx.x * blockDim.x + threadIdx.x;
    if (i < n) a[i] = 0;
}

// ---------------- bucket histogram (LDS-aggregated) ----------------
__global__ __launch_bounds__(256) void k_bcount(const int* __restrict__ dst,
                                                int* __restrict__ bcnt) {
    __shared__ int lc[NBUCK2];
    for (int b = threadIdx.x; b < NBUCK2; b += 256) lc[b] = 0;
    __syncthreads();
    for (int e = blockIdx.x * 256 + threadIdx.x; e < N_EDGES; e += gridDim.x * 256)
        atomicAdd(&lc[dst[e] >> BSHIFT2], 1);
    __syncthreads();
    for (int b = threadIdx.x; b < NBUCK2; b += 256)
        if (lc[b] > 0) atomicAdd(&bcnt[b], lc[b]);
}

// ---------------- 1024-wide scan of bucket counts -> bbase (exclusive) ----------------
__global__ __launch_bounds__(1024) void k_bscan(const int* __restrict__ bcnt,
                                                int* __restrict__ bbase) {
    __shared__ int tmp[1024];
    int i = threadIdx.x;
    int v = (i < NBUCK2) ? bcnt[i] : 0;
    tmp[i] = v;
    __syncthreads();
    for (int off = 1; off < 1024; off <<= 1) {
        int t = (i >= off) ? tmp[i - off] : 0;
        __syncthreads();
        tmp[i] += t;
        __syncthreads();
    }
    bbase[i] = tmp[i] - v;          // exclusive
    if (i == 1023) bbase[1024] = tmp[i];
}

// ---------------- bin edges into bucket-contiguous packed u32 stream ----------------
__global__ __launch_bounds__(256) void k_binwrite(const int* __restrict__ src,
                                                  const int* __restrict__ dst,
                                                  const int* __restrict__ bbase,
                                                  int* __restrict__ bcur,
                                                  uint_t* __restrict__ binned) {
    __shared__ int lcnt[NBUCK2];
    __shared__ int lpos[NBUCK2];
    for (int b = threadIdx.x; b < NBUCK2; b += 256) lcnt[b] = 0;
    __syncthreads();
    int e0 = blockIdx.x * BW_CHUNK;
    int e1 = e0 + BW_CHUNK; if (e1 > N_EDGES) e1 = N_EDGES;
    for (int e = e0 + threadIdx.x; e < e1; e += 256)
        atomicAdd(&lcnt[dst[e] >> BSHIFT2], 1);
    __syncthreads();
    for (int b = threadIdx.x; b < NBUCK2; b += 256) {
        int c = lcnt[b];
        lpos[b] = (c > 0) ? (bbase[b] + atomicAdd(&bcur[b], c)) : 0;
    }
    __syncthreads();
    for (int e = e0 + threadIdx.x; e < e1; e += 256) {
        int d = dst[e];
        int b = d >> BSHIFT2;
        int pos = atomicAdd(&lpos[b], 1);
        binned[pos] = (uint_t)src[e] | ((uint_t)(d & 127) << 17);
    }
}

// ---------------- per-bucket CSR build (one L2 window); emits rowptr, dinv ----------------
__global__ __launch_bounds__(256) void k_fill3(const int* __restrict__ bbase,
                                               const uint_t* __restrict__ binned,
                                               int* __restrict__ rowptr,
                                               float* __restrict__ dinv,
                                               int* __restrict__ csr) {
    __shared__ int cnt[128];
    __shared__ int tmp[128];
    __shared__ int pos[128];
    int b = blockIdx.x;
    int node0 = b << BSHIFT2;
    int lo = bbase[b], hi = bbase[b + 1];
    int t = threadIdx.x;
    if (t < 128) cnt[t] = 0;
    __syncthreads();
    for (int i = lo + t; i < hi; i += 256)
        atomicAdd(&cnt[binned[i] >> 17], 1);
    __syncthreads();
    if (t < 128) tmp[t] = cnt[t];
    __syncthreads();
    for (int o = 1; o < 128; o <<= 1) {
        int v = 0;
        if (t < 128 && t >= o) v = tmp[t - o];
        __syncthreads();
        if (t < 128) tmp[t] += v;
        __syncthreads();
    }
    if (t < 128) {
        int excl = tmp[t] - cnt[t];
        pos[t] = excl;
        int node = node0 + t;
        if (node < N_NODES) {
            rowptr[node] = lo + excl;
            dinv[node] = rsqrtf((float)cnt[t] + 1.0f);
        } else if (node == N_NODES) {
            rowptr[node] = lo + excl;
        }
    }
    __syncthreads();
    for (int i = lo + t; i < hi; i += 256) {
        uint_t v = binned[i];
        int dloc = v >> 17;
        int p = atomicAdd(&pos[dloc], 1);
        csr[lo + p] = (int)(v & SRC_MASK);
    }
}

// ---------------- W1 -> bf16, transposed+padded: Wt[n][k], n<64, k<512 ----------------
__global__ void k_cvtW(const float* __restrict__ W1, short* __restrict__ Wt) {
    int i = blockIdx.x * 256 + threadIdx.x;
    if (i < 64 * KPAD) {
        int n = i >> 9, k = i & (KPAD - 1);
        float v = (k < F0) ? W1[k * 64 + n] : 0.f;
        Wt[i] = f2bf(v);
    }
}

// ---------------- layer 1 MFMA GEMM, K-split x2 per block ----------------
// block = 256 (4 waves): 2 row-groups x 2 K-halves; 32 rows/block; grid = N/32.
__global__ __launch_bounds__(256) void k_gemm1_mfma(const float* __restrict__ x,
                                                    const short* __restrict__ Wt,
                                                    const float* __restrict__ dinv,
                                                    ushort_t* __restrict__ g1) {
    __shared__ float red[2 * 16 * 64];   // 8 KB: [rg][reg16][lane]
    int wave = threadIdx.x >> 6;
    int lane = threadIdx.x & 63;
    int rg = wave >> 1;                  // 0..1
    int khalf = wave & 1;                // 0..1
    int quad = lane >> 4;
    int m = lane & 15;
    int row0 = blockIdx.x * 32 + rg * 16;
    int row = row0 + m;
    int rowc = row < N_NODES ? row : N_NODES - 1;
    const float* xr = x + (size_t)rowc * F0;

    f32x4 acc0 = {0.f, 0.f, 0.f, 0.f};
    f32x4 acc1 = {0.f, 0.f, 0.f, 0.f};
    f32x4 acc2 = {0.f, 0.f, 0.f, 0.f};
    f32x4 acc3 = {0.f, 0.f, 0.f, 0.f};

    const short* wb = Wt + m * KPAD + quad * 8;

    if (khalf == 0) {
#pragma unroll
        for (int ks = 0; ks < 8; ks++) {
            int kb = ks * 32 + quad * 8;
            short8 af;
#pragma unroll
            for (int j = 0; j < 8; j++) af[j] = f2bf(xr[kb + j]);
            const short* wk = wb + ks * 32;
            short8 b0 = *(const short8*)(wk);
            short8 b1 = *(const short8*)(wk + 16 * KPAD);
            short8 b2 = *(const short8*)(wk + 32 * KPAD);
            short8 b3 = *(const short8*)(wk + 48 * KPAD);
            acc0 = __builtin_amdgcn_mfma_f32_16x16x32_bf16(af, b0, acc0, 0, 0, 0);
            acc1 = __builtin_amdgcn_mfma_f32_16x16x32_bf16(af, b1, acc1, 0, 0, 0);
            acc2 = __builtin_amdgcn_mfma_f32_16x16x32_bf16(af, b2, acc2, 0, 0, 0);
            acc3 = __builtin_amdgcn_mfma_f32_16x16x32_bf16(af, b3, acc3, 0, 0, 0);
        }
    } else {
#pragma unroll
        for (int ks = 8; ks < 15; ks++) {
            int kb = ks * 32 + quad * 8;
            short8 af;
#pragma unroll
            for (int j = 0; j < 8; j++) af[j] = f2bf(xr[kb + j]);
            const short* wk = wb + ks * 32;
            short8 b0 = *(const short8*)(wk);
            short8 b1 = *(const short8*)(wk + 16 * KPAD);
            short8 b2 = *(const short8*)(wk + 32 * KPAD);
            short8 b3 = *(const short8*)(wk + 48 * KPAD);
            acc0 = __builtin_amdgcn_mfma_f32_16x16x32_bf16(af, b0, acc0, 0, 0, 0);
            acc1 = __builtin_amdgcn_mfma_f32_16x16x32_bf16(af, b1, acc1, 0, 0, 0);
            acc2 = __builtin_amdgcn_mfma_f32_16x16x32_bf16(af, b2, acc2, 0, 0, 0);
            acc3 = __builtin_amdgcn_mfma_f32_16x16x32_bf16(af, b3, acc3, 0, 0, 0);
        }
        {   // ks = 15 tail
            int kb = 480 + quad * 8;
            short8 af;
#pragma unroll
            for (int j = 0; j < 8; j++) af[j] = (kb + j < F0) ? f2bf(xr[kb + j]) : (short)0;
            const short* wk = wb + 15 * 32;
            short8 b0 = *(const short8*)(wk);
            short8 b1 = *(const short8*)(wk + 16 * KPAD);
            short8 b2 = *(const short8*)(wk + 32 * KPAD);
            short8 b3 = *(const short8*)(wk + 48 * KPAD);
            acc0 = __builtin_amdgcn_mfma_f32_16x16x32_bf16(af, b0, acc0, 0, 0, 0);
            acc1 = __builtin_amdgcn_mfma_f32_16x16x32_bf16(af, b1, acc1, 0, 0, 0);
            acc2 = __builtin_amdgcn_mfma_f32_16x16x32_bf16(af, b2, acc2, 0, 0, 0);
            acc3 = __builtin_amdgcn_mfma_f32_16x16x32_bf16(af, b3, acc3, 0, 0, 0);
        }
    }

    float* myred = red + rg * 1024;
    if (khalf == 1) {
#pragma unroll
        for (int r = 0; r < 4; r++) {
            myred[(r + 0) * 64 + lane] = acc0[r];
            myred[(r + 4) * 64 + lane] = acc1[r];
            myred[(r + 8) * 64 + lane] = acc2[r];
            myred[(r + 12) * 64 + lane] = acc3[r];
        }
    }
    __syncthreads();
    if (khalf == 0) {
#pragma unroll
        for (int r = 0; r < 4; r++) {
            acc0[r] += myred[(r + 0) * 64 + lane];
            acc1[r] += myred[(r + 4) * 64 + lane];
            acc2[r] += myred[(r + 8) * 64 + lane];
            acc3[r] += myred[(r + 12) * 64 + lane];
        }
        // D layout: col = lane&15, row = quad*4 + reg
#pragma unroll
        for (int r = 0; r < 4; r++) {
            int orow = row0 + quad * 4 + r;
            if (orow < N_NODES) {
                float s = dinv[orow];
                ushort_t* gr = g1 + (size_t)orow * 64 + m;
                gr[0]  = (ushort_t)f2bf(s * acc0[r]);
                gr[16] = (ushort_t)f2bf(s * acc1[r]);
                gr[32] = (ushort_t)f2bf(s * acc2[r]);
                gr[48] = (ushort_t)f2bf(s * acc3[r]);
            }
        }
    }
}

// ---------------- gather64: dword (2-feature) loads, 2 edges per wave-step ----------------
__global__ __launch_bounds__(256) void k_gather64(const int* __restrict__ rowptr,
                                                  const int* __restrict__ csr,
                                                  const uint_t* __restrict__ g,
                                                  float* __restrict__ agg) {
    int node = blockIdx.x * 4 + (threadIdx.x >> 6);
    int lane = threadIdx.x & 63;
    int f2 = lane & 31;          // feature pair
    int which = lane >> 5;       // 0..1
    int beg = rowptr[node], end = rowptr[node + 1];
    float ax = 0.f, ay = 0.f, bx = 0.f, by = 0.f;
    if (which == 0) {
        uint_t sv = g[(size_t)node * 32 + f2];  // self loop
        ax = pair_lo(sv); ay = pair_hi(sv);
    }
    for (int j0 = beg; j0 < end; j0 += 64) {
        int n = end - j0;
        if (n > 64) n = 64;
        int ev = csr[j0 + (lane < n ? lane : n - 1)];
        int i = 0;
        for (; i + 4 <= n; i += 4) {
            int s0 = __shfl(ev, i + which, 64);
            int s1 = __shfl(ev, i + 2 + which, 64);
            uint_t d0 = g[(size_t)s0 * 32 + f2];
            uint_t d1 = g[(size_t)s1 * 32 + f2];
            ax += pair_lo(d0); ay += pair_hi(d0);
            bx += pair_lo(d1); by += pair_hi(d1);
        }
        for (; i < n; i += 2) {
            int idx = i + which;
            bool ok = idx < n;
            int s0 = __shfl(ev, ok ? idx : 0, 64);
            uint_t d0 = g[(size_t)s0 * 32 + f2];
            if (ok) { ax += pair_lo(d0); ay += pair_hi(d0); }
        }
    }
    ax += bx; ay += by;
    float tx = __shfl(ax, (lane + 32) & 63, 64);
    float ty = __shfl(ay, (lane + 32) & 63, 64);
    if (which == 0) {
        float2 o = make_float2(ax + tx, ay + ty);
        *reinterpret_cast<float2*>(agg + (size_t)node * 64 + f2 * 2) = o;
    }
}

// ---------------- gather32: dword loads, 4 edges per wave-step ----------------
__global__ __launch_bounds__(256) void k_gather32(const int* __restrict__ rowptr,
                                                  const int* __restrict__ csr,
                                                  const uint_t* __restrict__ g,
                                                  float* __restrict__ agg) {
    int node = blockIdx.x * 4 + (threadIdx.x >> 6);
    int lane = threadIdx.x & 63;
    int f2 = lane & 15;          // feature pair
    int which = lane >> 4;       // 0..3
    int beg = rowptr[node], end = rowptr[node + 1];
    float ax = 0.f, ay = 0.f, bx = 0.f, by = 0.f;
    if (which == 0) {
        uint_t sv = g[(size_t)node * 16 + f2];  // self loop
        ax = pair_lo(sv); ay = pair_hi(sv);
    }
    for (int j0 = beg; j0 < end; j0 += 64) {
        int n = end - j0;
        if (n > 64) n = 64;
        int ev = csr[j0 + (lane < n ? lane : n - 1)];
        int i = 0;
        for (; i + 8 <= n; i += 8) {
            int s0 = __shfl(ev, i + which, 64);
            int s1 = __shfl(ev, i + 4 + which, 64);
            uint_t d0 = g[(size_t)s0 * 16 + f2];
            uint_t d1 = g[(size_t)s1 * 16 + f2];
            ax += pair_lo(d0); ay += pair_hi(d0);
            bx += pair_lo(d1); by += pair_hi(d1);
        }
        for (; i < n; i += 4) {
            int idx = i + which;
            bool ok = idx < n;
            int s0 = __shfl(ev, ok ? idx : 0, 64);
            uint_t d0 = g[(size_t)s0 * 16 + f2];
            if (ok) { ax += pair_lo(d0); ay += pair_hi(d0); }
        }
    }
    ax += bx; ay += by;
    ax += __shfl(ax, (lane + 32) & 63, 64);
    ay += __shfl(ay, (lane + 32) & 63, 64);
    ax += __shfl(ax, (lane + 16) & 63, 64);
    ay += __shfl(ay, (lane + 16) & 63, 64);
    if (which == 0) {
        float2 o = make_float2(ax, ay);
        *reinterpret_cast<float2*>(agg + (size_t)node * 32 + f2 * 2) = o;
    }
}

// ---------------- gather, 2 fp32 features ----------------
__global__ __launch_bounds__(256) void k_gather2(const int* __restrict__ rowptr,
                                                 const int* __restrict__ csr,
                                                 const float* __restrict__ g,
                                                 float* __restrict__ agg) {
    int t = blockIdx.x * 256 + threadIdx.x;
    if (t >= N_NODES * 2) return;
    int node = t >> 1;
    int f = t & 1;
    int beg = rowptr[node], end = rowptr[node + 1];
    float acc = g[(size_t)node * 2 + f];
    for (int j = beg; j < end; j++) {
        int s = csr[j];
        acc += g[(size_t)s * 2 + f];
    }
    agg[(size_t)node * 2 + f] = acc;
}

// ---------------- layer 2: g2 = bf16( dinv .* (relu(dinv*agg1+b1) @ W2) ) ----------------
__global__ __launch_bounds__(256) void k_layer2(const float* __restrict__ agg1,
                                                const float* __restrict__ dinv,
                                                const float* __restrict__ b1,
                                                const float* __restrict__ W2,
                                                ushort_t* __restrict__ g2) {
    __shared__ float hs[32][65];
    __shared__ float Ws[64 * 32];
    for (int i = threadIdx.x; i < 64 * 32; i += 256) Ws[i] = W2[i];
    int row0 = blockIdx.x * 32;
    for (int i = threadIdx.x; i < 32 * 64; i += 256) {
        int r = i >> 6, f = i & 63;
        int row = row0 + r;
        float v = dinv[row] * agg1[(size_t)row * 64 + f] + b1[f];
        hs[r][f] = fmaxf(v, 0.f);
    }
    __syncthreads();
    int r = threadIdx.x >> 3;
    int j0 = (threadIdx.x & 7) * 4;
    int row = row0 + r;
    float a0 = 0.f, a1 = 0.f, a2 = 0.f, a3 = 0.f;
#pragma unroll 8
    for (int f = 0; f < 64; f++) {
        float h = hs[r][f];
        a0 += h * Ws[f * 32 + j0 + 0];
        a1 += h * Ws[f * 32 + j0 + 1];
        a2 += h * Ws[f * 32 + j0 + 2];
        a3 += h * Ws[f * 32 + j0 + 3];
    }
    float s = dinv[row];
    ushort_t* gr = g2 + (size_t)row * 32 + j0;
    gr[0] = (ushort_t)f2bf(s * a0);
    gr[1] = (ushort_t)f2bf(s * a1);
    gr[2] = (ushort_t)f2bf(s * a2);
    gr[3] = (ushort_t)f2bf(s * a3);
}

// ---------------- layer 3 ----------------
__global__ __launch_bounds__(256) void k_layer3(const float* __restrict__ agg2,
                                                const float* __restrict__ dinv,
                                                const float* __restrict__ b2,
                                                const float* __restrict__ W3,
                                                float* __restrict__ g3) {
    int row = blockIdx.x * blockDim.x + threadIdx.x;
    if (row >= N_NODES) return;
    float s = dinv[row];
    float t0 = 0.f, t1 = 0.f;
    const float4* ar = reinterpret_cast<const float4*>(agg2 + (size_t)row * 32);
#pragma unroll
    for (int q = 0; q < 8; q++) {
        float4 v = ar[q];
        float h;
        int f = q * 4;
        h = fmaxf(s * v.x + b2[f + 0], 0.f); t0 += h * W3[(f + 0) * 2]; t1 += h * W3[(f + 0) * 2 + 1];
        h = fmaxf(s * v.y + b2[f + 1], 0.f); t0 += h * W3[(f + 1) * 2]; t1 += h * W3[(f + 1) * 2 + 1];
        h = fmaxf(s * v.z + b2[f + 2], 0.f); t0 += h * W3[(f + 2) * 2]; t1 += h * W3[(f + 2) * 2 + 1];
        h = fmaxf(s * v.w + b2[f + 3], 0.f); t0 += h * W3[(f + 3) * 2]; t1 += h * W3[(f + 3) * 2 + 1];
    }
    g3[(size_t)row * 2 + 0] = s * t0;
    g3[(size_t)row * 2 + 1] = s * t1;
}

// ---------------- final log_softmax ----------------
__global__ void k_final(const float* __restrict__ agg3,
                        const float* __restrict__ dinv,
                        const float* __restrict__ b3,
                        float* __restrict__ out) {
    int row = blockIdx.x * blockDim.x + threadIdx.x;
    if (row >= N_NODES) return;
    float s = dinv[row];
    float z0 = s * agg3[(size_t)row * 2 + 0] + b3[0];
    float z1 = s * agg3[(size_t)row * 2 + 1] + b3[1];
    float m = fmaxf(z0, z1);
    float lse = m + logf(expf(z0 - m) + expf(z1 - m));
    out[(size_t)row * 2 + 0] = z0 - lse;
    out[(size_t)row * 2 + 1] = z1 - lse;
}

extern "C" void kernel_launch(void* const* d_in, const int* in_sizes, int n_in,
                              void* d_out, int out_size, void* d_ws, size_t ws_size,
                              hipStream_t stream) {
    const float* x  = (const float*)d_in[0];
    const int*   ei = (const int*)d_in[1];
    const float* W1 = (const float*)d_in[2];
    const float* b1 = (const float*)d_in[3];
    const float* W2 = (const float*)d_in[4];
    const float* b2 = (const float*)d_in[5];
    const float* W3 = (const float*)d_in[6];
    const float* b3 = (const float*)d_in[7];
    float* out = (float*)d_out;

    const int* src = ei;
    const int* dst = ei + N_EDGES;

    // ---- workspace layout (int elements) ----
    int* bcnt   = (int*)d_ws;                    // 1024
    int* bcur   = bcnt + 1024;                   // 1024  (zero bcnt+bcur = 2048)
    int* bbase  = bcur + 1024;                   // 1028
    int* rowptr = bbase + 1028;                  // 100004
    int* csr    = rowptr + 100004;               // 3200000
    float* dinv = (float*)(csr + 3200000);       // 100000
    short* Wt   = (short*)(dinv + 100000);       // 32768 shorts = 16384 ints
    uint_t* binned = (uint_t*)((int*)Wt + 16384);         // 3.2M u32 = 12.8 MB
    ushort_t* gbuf = (ushort_t*)(binned + N_EDGES);       // N*64 ushort = 12.8 MB
    float* aggF = (float*)(gbuf + (size_t)N_NODES * 64);  // N*64 fp32 = 25.6 MB

    ushort_t* gb1 = gbuf;
    ushort_t* gb2 = gbuf;
    float* g3     = (float*)gbuf;   // gb2 dead after gather32
    float* agg1 = aggF;
    float* agg2 = aggF;
    float* agg3 = aggF;

    const int TB = 256;
    int nb_nodes = (N_NODES + TB - 1) / TB;      // 391
    int nb_bw    = (N_EDGES + BW_CHUNK - 1) / BW_CHUNK;  // 196

    k_zero<<<8, TB, 0, stream>>>(bcnt, 2048);
    k_bcount<<<2048, TB, 0, stream>>>(dst, bcnt);
    k_bscan<<<1, 1024, 0, stream>>>(bcnt, bbase);
    k_binwrite<<<nb_bw, TB, 0, stream>>>(src, dst, bbase, bcur, binned);
    k_fill3<<<NBUCK2, TB, 0, stream>>>(bbase, binned, rowptr, dinv, csr);
    k_cvtW<<<(64 * KPAD + 255) / 256, 256, 0, stream>>>(W1, Wt);

    k_gemm1_mfma<<<N_NODES / 32, TB, 0, stream>>>(x, Wt, dinv, gb1);
    k_gather64<<<N_NODES / 4, TB, 0, stream>>>(rowptr, csr, (const uint_t*)gb1, agg1);

    k_layer2<<<N_NODES / 32, TB, 0, stream>>>(agg1, dinv, b1, W2, gb2);
    k_gather32<<<N_NODES / 4, TB, 0, stream>>>(rowptr, csr, (const uint_t*)gb2, agg2);

    k_layer3<<<nb_nodes, TB, 0, stream>>>(agg2, dinv, b2, W3, g3);
    k_gather2<<<(2 * N_NODES + TB - 1) / TB, TB, 0, stream>>>(rowptr, csr, g3, agg3);

    k_final<<<nb_nodes, TB, 0, stream>>>(agg3, dinv, b3, out);
}